// Round 5
// baseline (638.734 us; speedup 1.0000x reference)
//
#include <hip/hip_runtime.h>

typedef short short8 __attribute__((ext_vector_type(8)));
typedef short short4v __attribute__((ext_vector_type(4)));
typedef float f32x4 __attribute__((ext_vector_type(4)));

#define DEVINL __device__ __forceinline__

// ---------------- host: sedenion sign/index table (Cayley-Dickson) ----------
struct SedTab { signed char s[256]; unsigned char j[256]; };

static void cd_mult_host(const float* a, const float* b, float* r, int n) {
    if (n == 1) { r[0] = a[0] * b[0]; return; }
    int h = n / 2;
    float cb1[8], cb2[8], t1[8], t2[8], t3[8], t4[8];
    cb1[0] = b[0]; for (int i = 1; i < h; ++i) cb1[i] = -b[i];        // conj(b1)
    cb2[0] = b[h]; for (int i = 1; i < h; ++i) cb2[i] = -b[h + i];    // conj(b2)
    cd_mult_host(a,     b,   t1, h);   // a1*b1
    cd_mult_host(cb2,   a+h, t2, h);   // conj(b2)*a2
    cd_mult_host(b+h,   a,   t3, h);   // b2*a1
    cd_mult_host(a+h,   cb1, t4, h);   // a2*conj(b1)
    for (int i = 0; i < h; ++i) { r[i] = t1[i] - t2[i]; r[h + i] = t3[i] + t4[i]; }
}

static SedTab build_sed() {
    SedTab t{};
    for (int i = 0; i < 16; ++i)
        for (int jj = 0; jj < 16; ++jj) {
            float a[16] = {0}, b[16] = {0}, r[16] = {0};
            a[i] = 1.0f; b[jj] = 1.0f;
            cd_mult_host(a, b, r, 16);
            for (int k = 0; k < 16; ++k)
                if (r[k] != 0.0f) {
                    t.s[i * 16 + k] = (r[k] > 0.f) ? 1 : -1;
                    t.j[i * 16 + k] = (unsigned char)jj;
                }
        }
    return t;
}
static const SedTab g_sed = build_sed();

// ---------------- device helpers -------------------------------------------
DEVINL unsigned short f2bf(float v) {
    union { float f; unsigned int u; } c; c.f = v;
    unsigned int r = (c.u + 0x7FFFu + ((c.u >> 16) & 1u)) >> 16;
    return (unsigned short)r;
}
DEVINL unsigned int pack2bf(float a, float b) {
    union { float f; unsigned int u; } ca, cb; ca.f = a; cb.f = b;
    unsigned int ra = (ca.u + 0x7FFFu + ((ca.u >> 16) & 1u)) >> 16;
    unsigned int rb = (cb.u + 0x7FFFu + ((cb.u >> 16) & 1u)) & 0xFFFF0000u;
    return ra | rb;
}
DEVINL float bf2f(unsigned short u) {
    union { unsigned int i; float f; } c; c.i = ((unsigned int)u) << 16; return c.f;
}

DEVINL float gelu_f(float v) {   // tanh-approx == v*sigmoid(1.5958(v+0.044715v^3)), |err|<1.1e-3
    float u = 1.5957691216f * (v + 0.044715f * v * v * v);
    return v / (1.0f + __expf(-u));
}

DEVINL void gl2lds16(const void* g, void* l) {
    __builtin_amdgcn_global_load_lds((__attribute__((address_space(1))) const unsigned int*)g,
                                     (__attribute__((address_space(3))) unsigned int*)l, 16, 0, 0);
}

// xor-swizzle position of element k within a row (64-groups, chunks of 8)
DEVINL int swz(int k, int row) {
    return (k & ~63) | ((((k >> 3) ^ row) & 7) << 3) | (k & 7);
}
// xor-swizzle within 32-groups, 4 chunks of 8
DEVINL int swz32(int k, int row) {
    return (k & ~31) | ((((k >> 3) ^ row) & 3) << 3) | (k & 7);
}

// ---------------- wfT builder: wfT[n=(k,e)][kk=(i,dd)] = s(i,k)*w_sed[j,dd,e]
__global__ __launch_bounds__(256) void build_wft(const float* __restrict__ w_sed,
                                                 unsigned short* __restrict__ wfT,
                                                 SedTab tab) {
    __shared__ float t[32][33];
    int n0 = blockIdx.y * 32, kk0 = blockIdx.x * 32;
    int k = n0 / 192, i = kk0 / 192;            // tiles never straddle (192 = 6*32)
    int j = tab.j[i * 16 + k];
    float s = (float)tab.s[i * 16 + k];
    int e0 = n0 - k * 192, dd0 = kk0 - i * 192;
    int tx = threadIdx.x & 31, ty = threadIdx.x >> 5;
    const float* base = w_sed + ((size_t)j * 192 + dd0) * 192 + e0;
    for (int it = 0; it < 4; ++it) {
        int row = ty + it * 8;                  // row = dd index, tx = e index
        t[row][tx] = base[(size_t)row * 192 + tx];
    }
    __syncthreads();
    unsigned short* ob = wfT + (size_t)n0 * 3072 + kk0;
    for (int it = 0; it < 4; ++it) {
        int row = ty + it * 8;                  // out row = e index, tx = dd index
        ob[(size_t)row * 3072 + tx] = f2bf(s * t[tx][row]);
    }
}

// ---------------- small weights → bf16 (pre-swizzled for LDS) ---------------
__global__ __launch_bounds__(256) void prep_w(const float* __restrict__ proj,
                                              const float* __restrict__ fc1,
                                              const float* __restrict__ fc2,
                                              unsigned short* __restrict__ projT,
                                              unsigned short* __restrict__ fc1T,
                                              unsigned short* __restrict__ fc2S) {
    int t = blockIdx.x * 256 + threadIdx.x;     // grid covers 147456
    if (t < 192 * 192) projT[t] = f2bf(proj[(t % 192) * 192 + t / 192]);
    if (t < 768 * 192) {
        int n = t / 192, k = t % 192;           // fc1T[h][c], 64-group swizzle
        fc1T[n * 192 + swz(k, n)] = f2bf(fc1[(size_t)k * 768 + n]);
    }
    if (t < 192 * 768) {
        int o = t / 768, h = t % 768;           // fc2S[o][h], 32-group swizzle
        fc2S[o * 768 + swz32(h, o)] = f2bf(fc2[(size_t)h * 192 + o]);
    }
}

// ---------------- LN1 over channels + windowize; also emit raw x (bf16) -----
__global__ __launch_bounds__(256) void ln1_win(const float* __restrict__ x,
                                               const float* __restrict__ g,
                                               const float* __restrict__ bta,
                                               unsigned short* __restrict__ xw,
                                               unsigned short* __restrict__ xwin) {
    __shared__ float vals[192 * 65];
    __shared__ float ps[8][64];
    __shared__ float mrs[2][64];
    int t = threadIdx.x;
    int bid = blockIdx.x;
    int x0 = (bid & 3) << 6;
    int y  = (bid >> 2) & 255;
    int b  = bid >> 10;
    int px = t & 63, cg = t >> 6;
    const float* xp = x + ((size_t)b * 192 * 65536) + (size_t)y * 256 + x0 + px;
    float s = 0.f, s2 = 0.f;
    for (int c = cg; c < 192; c += 4) {
        float v = xp[(size_t)c * 65536];
        vals[c * 65 + px] = v;
        s += v; s2 += v * v;
    }
    ps[cg][px] = s; ps[cg + 4][px] = s2;
    __syncthreads();
    if (t < 64) {
        float S  = ps[0][t] + ps[1][t] + ps[2][t] + ps[3][t];
        float S2 = ps[4][t] + ps[5][t] + ps[6][t] + ps[7][t];
        float mean = S * (1.0f / 192.0f);
        float var  = S2 * (1.0f / 192.0f) - mean * mean;
        mrs[0][t] = mean;
        mrs[1][t] = rsqrtf(var + 1e-5f);
    }
    __syncthreads();
    int wh = y >> 2, wr = y & 3;
    for (int i = t; i < 192 * 64; i += 256) {
        int p = i / 192;
        int c = i - p * 192;
        float v = vals[c * 65 + p];
        int xx = x0 + p;
        int ww = xx >> 2, wc = xx & 3;
        int gp = ((b * 64 + wh) * 64 + ww) * 16 + wr * 4 + wc;
        size_t o = (size_t)gp * 192 + c;
        xwin[o] = f2bf(v);
        xw[o] = f2bf((v - mrs[0][p]) * mrs[1][p] * g[c] + bta[c]);
    }
}

// ---------------- bf16 MFMA GEMM, TM x TN, BK=64, XOR-swizzled LDS ----------
// EPI 0: outB bf16 = gelu(acc)                                (gemm1 sedenion)
// EPI 3: xres(bf16) += acc+bias; outB = LN2(xres) bf16 plain  (gemm2 proj)
template<int TM, int TN, int EPI>
__global__ __launch_bounds__(256, 2) void gemm_bf16(
        const unsigned short* __restrict__ A, const unsigned short* __restrict__ BT,
        const float* __restrict__ bias, unsigned short* __restrict__ outB,
        unsigned short* __restrict__ xresb,
        const float* __restrict__ g2, const float* __restrict__ b2,
        int K, int N) {
    constexpr int WN = TN / 2;
    constexpr int NT = WN / 16;
    constexpr int MT = TM / 32;
    constexpr int HR = TM / 2;
    __shared__ __align__(16) char smem[(TM * 64 + TN * 64) * 2];
    short* lsA = (short*)smem;
    short* lsB = (short*)(smem + TM * 64 * 2);
    int tid = threadIdx.x, lane = tid & 63, wid = tid >> 6;
    int wrow = wid >> 1, wcol = wid & 1;
    int lm = lane & 15, lq = lane >> 4;
    int bm = blockIdx.x * TM, bn = blockIdx.y * TN;
    const unsigned short* Ag = A + (size_t)bm * K;
    const unsigned short* Bg = BT + (size_t)bn * K;
    f32x4 acc[MT][NT] = {};
    for (int k0 = 0; k0 < K; k0 += 64) {
        #pragma unroll
        for (int it = 0; it < TM / 32; ++it) {      // stage A tile
            int p = (it * 4 + wid) * 64 + lane;
            int r = p >> 3;
            int q = (p & 7) ^ (r & 7);
            gl2lds16(Ag + (size_t)r * K + k0 + q * 8, lsA + (it * 4 + wid) * 512);
        }
        #pragma unroll
        for (int it = 0; it < TN / 32; ++it) {      // stage BT tile
            int p = (it * 4 + wid) * 64 + lane;
            int r = p >> 3;
            int q = (p & 7) ^ (r & 7);
            gl2lds16(Bg + (size_t)r * K + k0 + q * 8, lsB + (it * 4 + wid) * 512);
        }
        __syncthreads();
        #pragma unroll
        for (int s = 0; s < 2; ++s) {
            short8 af[MT], bfr[NT];
            #pragma unroll
            for (int mt = 0; mt < MT; ++mt) {
                int r = wrow * HR + mt * 16 + lm;
                int q = s * 4 + lq;
                int pos = r * 8 + (q ^ (r & 7));
                af[mt] = *(const short8*)&lsA[pos * 8];
            }
            #pragma unroll
            for (int nt = 0; nt < NT; ++nt) {
                int r = wcol * WN + nt * 16 + lm;
                int q = s * 4 + lq;
                int pos = r * 8 + (q ^ (r & 7));
                bfr[nt] = *(const short8*)&lsB[pos * 8];
            }
            #pragma unroll
            for (int mt = 0; mt < MT; ++mt)
                #pragma unroll
                for (int nt = 0; nt < NT; ++nt)
                    acc[mt][nt] = __builtin_amdgcn_mfma_f32_16x16x32_bf16(af[mt], bfr[nt], acc[mt][nt], 0, 0, 0);
        }
        __syncthreads();
    }
    // epilogue: C/D layout col=lane&15, row=lq*4+reg
    int rowB = bm + wrow * HR + lq * 4;
    int colB = bn + wcol * WN + lm;

    if constexpr (EPI == 0) {
        #pragma unroll
        for (int mt = 0; mt < MT; ++mt)
            #pragma unroll
            for (int nt = 0; nt < NT; ++nt)
                #pragma unroll
                for (int r = 0; r < 4; ++r) {
                    int gr = rowB + mt * 16 + r;
                    int gc = colB + nt * 16;
                    float v = acc[mt][nt][r];
                    if (bias) v += bias[gc];
                    outB[(size_t)gr * N + gc] = f2bf(gelu_f(v));
                }
    } else {
        // proj + residual into xres (bf16 in-place), fused LN2 → outB (plain)
        float sA[MT][4], s2A[MT][4];
        #pragma unroll
        for (int mt = 0; mt < MT; ++mt)
            #pragma unroll
            for (int r = 0; r < 4; ++r) { sA[mt][r] = 0.f; s2A[mt][r] = 0.f; }
        #pragma unroll
        for (int mt = 0; mt < MT; ++mt)
            #pragma unroll
            for (int nt = 0; nt < NT; ++nt)
                #pragma unroll
                for (int r = 0; r < 4; ++r) {
                    int gr = rowB + mt * 16 + r;
                    int gc = colB + nt * 16;
                    size_t o = (size_t)gr * 192 + gc;
                    float v = bf2f(xresb[o]) + acc[mt][nt][r] + bias[gc];
                    xresb[o] = f2bf(v);
                    acc[mt][nt][r] = v;
                    sA[mt][r] += v; s2A[mt][r] += v * v;
                }
        #pragma unroll
        for (int mt = 0; mt < MT; ++mt)
            #pragma unroll
            for (int r = 0; r < 4; ++r)
                #pragma unroll
                for (int msk = 1; msk < 16; msk <<= 1) {
                    sA[mt][r]  += __shfl_xor(sA[mt][r],  msk, 64);
                    s2A[mt][r] += __shfl_xor(s2A[mt][r], msk, 64);
                }
        float* psS   = (float*)smem;             // [128][2]
        float* psS2  = psS + 256;                // [128][2]
        float* pmean = psS2 + 256;               // [128]
        float* prsig = pmean + 128;              // [128]
        if (lm == 0) {
            #pragma unroll
            for (int mt = 0; mt < MT; ++mt)
                #pragma unroll
                for (int r = 0; r < 4; ++r) {
                    int rl = wrow * HR + mt * 16 + lq * 4 + r;
                    psS [rl * 2 + wcol] = sA[mt][r];
                    psS2[rl * 2 + wcol] = s2A[mt][r];
                }
        }
        __syncthreads();
        if (tid < TM) {
            float S  = psS[tid * 2]  + psS[tid * 2 + 1];
            float S2 = psS2[tid * 2] + psS2[tid * 2 + 1];
            float mean = S * (1.0f / 192.0f);
            float var  = S2 * (1.0f / 192.0f) - mean * mean;
            pmean[tid] = mean;
            prsig[tid] = rsqrtf(var + 1e-5f);
        }
        __syncthreads();
        float gw[NT], bw[NT];
        #pragma unroll
        for (int nt = 0; nt < NT; ++nt) {
            int gc = colB + nt * 16;
            gw[nt] = g2[gc]; bw[nt] = b2[gc];
        }
        #pragma unroll
        for (int mt = 0; mt < MT; ++mt)
            #pragma unroll
            for (int nt = 0; nt < NT; ++nt)
                #pragma unroll
                for (int r = 0; r < 4; ++r) {
                    int gr = rowB + mt * 16 + r;
                    int rl = wrow * HR + mt * 16 + lq * 4 + r;
                    int gc = colB + nt * 16;
                    float v = (acc[mt][nt][r] - pmean[rl]) * prsig[rl] * gw[nt] + bw[nt];
                    outB[(size_t)gr * 192 + gc] = f2bf(v);
                }
    }
}

// ---------------- fused FFN v2: register-resident S, operand-swapped --------
// Per block: 64 windowed-pixel rows. nb loop: 24 h-slices of 32.
// Phase A: Sᵀ = fc1slice(A-op) · A3(B-op, in regs)  → C-layout col = m
// gelu+pack → each lane (lm,lq') holds packs (t,lq') = h {t*16+lq'*4+0..3}
// Butterfly: dest (lm,lq) needs packs (t=lq>>1, lq'=(lq&1)*2 and +1) — each
// pack consumed by exactly one dest, but one __shfl moves one source reg, so
// publish BOTH P[0] and P[1] (8 shuffles) and select dest-side by lq>>1.
// Phase B: Oᵀ = fc2slice(A-op) · Sfrag(B-op) — lane holds O row for its pixel
__global__ __launch_bounds__(256, 4) void ffn_fused(
        const unsigned short* __restrict__ A3, const unsigned short* __restrict__ fc1T,
        const unsigned short* __restrict__ fc2S, const float* __restrict__ b1,
        const float* __restrict__ b2, const unsigned short* __restrict__ xresb,
        float* __restrict__ outF) {
    __shared__ __align__(16) short wA[32 * 192];   // fc1 slice [32 h][192 c]
    __shared__ __align__(16) short wB[192 * 32];   // fc2 slice [192 o][32 h]
    __shared__ float b1s[768];
    __shared__ float b2s[192];
    int tid = threadIdx.x, lane = tid & 63, wid = tid >> 6;
    int lm = lane & 15, lq = lane >> 4;
    int bm = blockIdx.x * 64;

    for (int i = tid; i < 768; i += 256) b1s[i] = b1[i];
    if (tid < 192) b2s[tid] = b2[tid];

    // A3 fragments in registers (B-operand: lane n=m=lm, k = lq*8+j)
    const unsigned short* A3r = A3 + (size_t)(bm + wid * 16 + lm) * 192;
    short8 a3f[6];
    #pragma unroll
    for (int ks = 0; ks < 6; ++ks)
        a3f[ks] = *(const short8*)(A3r + ks * 32 + lq * 8);

    int srcA = lm + ((lq & 1) << 5);      // source lanes: lq' = (lq&1)*2, +1
    int srcB = srcA + 16;
    bool hi = (lq >> 1) != 0;             // which t-pack this dest consumes

    f32x4 acc2[12] = {};
    for (int nb = 0; nb < 24; ++nb) {
        // stage fc1 slice (6144 shorts) + fc2 slice (6144 shorts)
        const unsigned short* f1g = fc1T + (size_t)nb * 32 * 192;
        #pragma unroll
        for (int it = 0; it < 3; ++it) {
            int ch = it * 4 + wid;
            gl2lds16(f1g + ch * 512 + lane * 8, wA + ch * 512);
        }
        #pragma unroll
        for (int it = 0; it < 3; ++it) {
            int ch = it * 4 + wid;
            int gch = ch * 64 + lane;               // 0..767
            gl2lds16(fc2S + (size_t)(gch >> 2) * 768 + nb * 32 + (gch & 3) * 8,
                     wB + ch * 512);
        }
        __syncthreads();

        // phase A: Sᵀ_pre[h][m], 2 h-tiles × 1 m-tile per wave
        f32x4 acc1[2] = {};
        #pragma unroll
        for (int ks = 0; ks < 6; ++ks) {
            short8 af[2];
            #pragma unroll
            for (int t = 0; t < 2; ++t) {
                int row = t * 16 + lm;
                int cc = ks * 4 + lq;
                int slot = (cc & ~7) | ((cc ^ row) & 7);
                af[t] = *(const short8*)&wA[row * 192 + slot * 8];
            }
            #pragma unroll
            for (int t = 0; t < 2; ++t)
                acc1[t] = __builtin_amdgcn_mfma_f32_16x16x32_bf16(af[t], a3f[ks], acc1[t], 0, 0, 0);
        }
        // gelu + bias, pack pairs
        unsigned int P[2][2];
        #pragma unroll
        for (int t = 0; t < 2; ++t) {
            f32x4 bv = *(const f32x4*)&b1s[nb * 32 + t * 16 + lq * 4];
            float g0 = gelu_f(acc1[t][0] + bv[0]);
            float g1 = gelu_f(acc1[t][1] + bv[1]);
            float g2 = gelu_f(acc1[t][2] + bv[2]);
            float g3 = gelu_f(acc1[t][3] + bv[3]);
            P[t][0] = pack2bf(g0, g1);
            P[t][1] = pack2bf(g2, g3);
        }
        // butterfly: publish both t-packs, dest selects by hi
        int a0 = __shfl((int)P[0][0], srcA, 64);
        int a1 = __shfl((int)P[0][1], srcA, 64);
        int a2 = __shfl((int)P[0][0], srcB, 64);
        int a3 = __shfl((int)P[0][1], srcB, 64);
        int c0 = __shfl((int)P[1][0], srcA, 64);
        int c1 = __shfl((int)P[1][1], srcA, 64);
        int c2 = __shfl((int)P[1][0], srcB, 64);
        int c3 = __shfl((int)P[1][1], srcB, 64);
        union { int i[4]; short8 v; } sf;
        sf.i[0] = hi ? c0 : a0;   // h = lq*8+0,1
        sf.i[1] = hi ? c1 : a1;   // h = lq*8+2,3
        sf.i[2] = hi ? c2 : a2;   // h = lq*8+4,5
        sf.i[3] = hi ? c3 : a3;   // h = lq*8+6,7

        // phase B: acc2[nt] (Oᵀ): A-op = fc2 slice, B-op = S fragment
        #pragma unroll
        for (int nt = 0; nt < 12; ++nt) {
            int o = nt * 16 + lm;
            int slot = lq ^ (o & 3);
            short8 wf = *(const short8*)&wB[o * 32 + slot * 8];
            acc2[nt] = __builtin_amdgcn_mfma_f32_16x16x32_bf16(wf, sf.v, acc2[nt], 0, 0, 0);
        }
        __syncthreads();
    }

    // epilogue: lane owns pixel mg = bm + wid*16 + lm, O values o = nt*16+lq*4+r
    int mg = bm + wid * 16 + lm;
    const unsigned short* xr = xresb + (size_t)mg * 192;
    int b  = mg >> 16;
    int wh = (mg >> 10) & 63;
    int ww = (mg >> 4) & 63;
    int y  = wh * 4 + (lm >> 2);
    int xx = ww * 4 + (lm & 3);
    float* obase = outF + (((size_t)b * 192 + lq * 4) * 256 + y) * 256 + xx;
    #pragma unroll
    for (int nt = 0; nt < 12; ++nt) {
        f32x4 b2v = *(const f32x4*)&b2s[nt * 16 + lq * 4];
        short4v xv = *(const short4v*)(xr + nt * 16 + lq * 4);
        #pragma unroll
        for (int r = 0; r < 4; ++r) {
            float v = acc2[nt][r] + b2v[r] + bf2f((unsigned short)xv[r]);
            obase[(size_t)(nt * 16 + r) * 65536] = v;
        }
    }
}

// ---------------- launch ----------------------------------------------------
extern "C" void kernel_launch(void* const* d_in, const int* in_sizes, int n_in,
                              void* d_out, int out_size, void* d_ws, size_t ws_size,
                              hipStream_t stream) {
    const float* x      = (const float*)d_in[0];
    const float* n1g    = (const float*)d_in[1];
    const float* n1b    = (const float*)d_in[2];
    const float* w_sed  = (const float*)d_in[3];
    const float* proj_w = (const float*)d_in[4];
    const float* proj_b = (const float*)d_in[5];
    const float* n2g    = (const float*)d_in[6];
    const float* n2b    = (const float*)d_in[7];
    const float* fc1_w  = (const float*)d_in[8];
    const float* fc1_b  = (const float*)d_in[9];
    const float* fc2_w  = (const float*)d_in[10];
    const float* fc2_b  = (const float*)d_in[11];
    float* out = (float*)d_out;

    char* ws = (char*)d_ws;
    unsigned short* wfT   = (unsigned short*)(ws);                 // 18,874,368 B
    unsigned short* xw    = (unsigned short*)(ws + 18874368);      // 50,331,648 B
    unsigned short* A2    = (unsigned short*)(ws + 69206016);      // 50,331,648 B (later A3, aliased safely)
    unsigned short* xresb = (unsigned short*)(ws + 119537664);     // 50,331,648 B (xwin, then xres in-place)
    unsigned short* projT = (unsigned short*)(ws + 169869312);     // 73,728 B
    unsigned short* fc1T  = (unsigned short*)(ws + 169943040);     // 294,912 B
    unsigned short* fc2S  = (unsigned short*)(ws + 170237952);     // 294,912 B (end 170,532,864)
    unsigned short* A3    = A2;   // EPI3 writes A3 rows only after reading same A2 rows — safe

    build_wft<<<dim3(96, 96), 256, 0, stream>>>(w_sed, wfT, g_sed);
    prep_w<<<576, 256, 0, stream>>>(proj_w, fc1_w, fc2_w, projT, fc1T, fc2S);
    ln1_win<<<2048, 256, 0, stream>>>(x, n1g, n1b, xw, xresb);

    // sedenion GEMM: [8192,3072]@[3072,3072] → gelu → A2 (≡ [131072,192])
    gemm_bf16<128, 128, 0><<<dim3(64, 24), 256, 0, stream>>>(
        xw, wfT, nullptr, A2, nullptr, nullptr, nullptr, 3072, 3072);
    // proj GEMM + residual(bf16, in-place) + fused LN2 → A3 (plain layout)
    gemm_bf16<128, 192, 3><<<dim3(1024, 1), 256, 0, stream>>>(
        A2, projT, proj_b, A3, xresb, n2g, n2b, 192, 192);
    // fused FFN v2: register-resident S, no H1 traffic
    ffn_fused<<<2048, 256, 0, stream>>>(A3, fc1T, fc2S, fc1_b, fc2_b, xresb, out);
}